// Round 4
// baseline (19.055 us; speedup 1.0000x reference)
//
#include <hip/hip_runtime.h>
#include <math.h>

// NN-MSE (one-directional Chamfer) loss — SINGLE dispatch.
//  Each of 256 blocks (512 thr = 8 waves): one segment b, 128 sources, full
//  per-source min over ALL S targets (waves split targets 8-way, LDS tile in
//  premultiplied (-2x,-2y,-2z,|t|^2) form, broadcast ds_read_b128).
//  Block partial sums are combined by the LAST block to finish (ticket
//  counter, agent-scope release/acquire) -> out[0]. No second kernel.
//
// Counter correctness without init: each call adds exactly nblk tickets; any
// nblk consecutive integers contain exactly one ticket == nblk-1 (mod nblk),
// so exactly one block finishes per call, for ANY starting counter value
// (garbage, poison, or accumulated across graph replays).

#define THREADS 512      // 8 waves
#define NW 8
#define P 2
#define SRC_BLK 128      // 64 lanes * P

__global__ __launch_bounds__(THREADS)
void nn_fused_kernel(const float* __restrict__ coord,
                     const float* __restrict__ coord_t,
                     const float* __restrict__ Rm,
                     const float* __restrict__ tv,
                     float* __restrict__ ws_part,       // [nblk]
                     unsigned int* __restrict__ counter,
                     float* __restrict__ out,
                     int S, int NSC, int nblk, float scale) {
    extern __shared__ char smem_raw[];
    float4* tile = (float4*)smem_raw;                       // S float4
    float*  part = (float*)(smem_raw + (size_t)S * 16);     // NW*64*P floats
    float*  wsum = part + NW * 64 * P;                      // 2 floats
    int*    flagp = (int*)(wsum + 2);                       // 1 int

    const int tid  = threadIdx.x;
    const int bid  = blockIdx.x;
    const int b    = bid / NSC;
    const int sc   = bid - b * NSC;
    const int w    = tid >> 6;
    const int lane = tid & 63;

    // ---- stage ALL S targets as (-2x,-2y,-2z,|t|^2); 4 points/thread ----
    {
        const float* tb = coord_t + (size_t)b * S * 3;
        for (int base = tid * 4; base < S; base += THREADS * 4) {
            const float4* g4 = reinterpret_cast<const float4*>(tb + (size_t)base * 3);
            const float4 q0 = g4[0], q1 = g4[1], q2 = g4[2];
            const float px[4] = {q0.x, q0.w, q1.z, q2.y};
            const float py[4] = {q0.y, q1.x, q1.w, q2.z};
            const float pz[4] = {q0.z, q1.y, q2.x, q2.w};
            #pragma unroll
            for (int k = 0; k < 4; ++k) {
                const float x = px[k], y = py[k], z = pz[k];
                tile[base + k] = make_float4(-2.f*x, -2.f*y, -2.f*z,
                                             x*x + y*y + z*z);
            }
        }
    }

    // ---- rigid transform params (block-uniform) ----
    const float* Rb = Rm + (size_t)b * 9;
    const float r00=Rb[0], r01=Rb[1], r02=Rb[2];
    const float r10=Rb[3], r11=Rb[4], r12=Rb[5];
    const float r20=Rb[6], r21=Rb[7], r22=Rb[8];
    const float t0=tv[3*b], t1=tv[3*b+1], t2=tv[3*b+2];

    // ---- this lane's P=2 source points, transformed ----
    float TX[P], TY[P], TZ[P], SN[P], best[P];
    {
        const float* sp = coord + ((size_t)b * S + (size_t)sc * SRC_BLK + lane * P) * 3;
        #pragma unroll
        for (int j = 0; j < P; ++j) {
            const float x = sp[3*j], y = sp[3*j+1], z = sp[3*j+2];
            const float sx = __builtin_fmaf(r00,x,__builtin_fmaf(r01,y,__builtin_fmaf(r02,z,t0)));
            const float sy = __builtin_fmaf(r10,x,__builtin_fmaf(r11,y,__builtin_fmaf(r12,z,t1)));
            const float sz = __builtin_fmaf(r20,x,__builtin_fmaf(r21,y,__builtin_fmaf(r22,z,t2)));
            TX[j]=sx; TY[j]=sy; TZ[j]=sz;
            SN[j]=sx*sx + sy*sy + sz*sz;
            best[j] = 3.0e38f;
        }
    }

    __syncthreads();

    // ---- main loop: wave w scans its S/NW targets, 4 per iteration ----
    const int mPer  = S / NW;
    const int mbase = w * mPer;
    #pragma unroll 2
    for (int it = 0; it < mPer / 4; ++it) {
        const float4 p0 = tile[mbase + 4*it + 0];
        const float4 p1 = tile[mbase + 4*it + 1];
        const float4 p2 = tile[mbase + 4*it + 2];
        const float4 p3 = tile[mbase + 4*it + 3];
        #pragma unroll
        for (int j = 0; j < P; ++j) {
            const float v0 = __builtin_fmaf(p0.x,TX[j],__builtin_fmaf(p0.y,TY[j],__builtin_fmaf(p0.z,TZ[j],p0.w)));
            const float v1 = __builtin_fmaf(p1.x,TX[j],__builtin_fmaf(p1.y,TY[j],__builtin_fmaf(p1.z,TZ[j],p1.w)));
            const float v2 = __builtin_fmaf(p2.x,TX[j],__builtin_fmaf(p2.y,TY[j],__builtin_fmaf(p2.z,TZ[j],p2.w)));
            const float v3 = __builtin_fmaf(p3.x,TX[j],__builtin_fmaf(p3.y,TY[j],__builtin_fmaf(p3.z,TZ[j],p3.w)));
            best[j] = fminf(fminf(best[j], v0), v1);   // v_min3
            best[j] = fminf(fminf(best[j], v2), v3);   // v_min3
        }
    }

    // ---- fold |s|^2; min across 8 waves; clamp; block sum ----
    #pragma unroll
    for (int j = 0; j < P; ++j)
        part[tid * P + j] = best[j] + SN[j];
    __syncthreads();

    float v = 0.0f;
    if (tid < SRC_BLK) {
        float mn = part[tid];                        // stride-1, conflict-free
        #pragma unroll
        for (int ww = 1; ww < NW; ++ww)
            mn = fminf(mn, part[ww * SRC_BLK + tid]);
        v = fmaxf(mn, 0.0f);
    }
    if (tid < 128) {
        #pragma unroll
        for (int off = 32; off > 0; off >>= 1) v += __shfl_down(v, off, 64);
        if ((tid & 63) == 0) wsum[tid >> 6] = v;
    }
    __syncthreads();

    // ---- publish partial; ticket; last block finishes ----
    if (tid == 0) {
        const float bsum = wsum[0] + wsum[1];
        __hip_atomic_store(ws_part + bid, bsum,
                           __ATOMIC_RELEASE, __HIP_MEMORY_SCOPE_AGENT);
        const unsigned t = __hip_atomic_fetch_add(counter, 1u,
                           __ATOMIC_ACQ_REL, __HIP_MEMORY_SCOPE_AGENT);
        *flagp = ((t % (unsigned)nblk) == (unsigned)(nblk - 1)) ? 1 : 0;
    }
    __syncthreads();

    if (*flagp) {
        float pv = 0.0f;
        if (tid < nblk)
            pv = __hip_atomic_load(ws_part + tid,
                                   __ATOMIC_RELAXED, __HIP_MEMORY_SCOPE_AGENT);
        #pragma unroll
        for (int off = 32; off > 0; off >>= 1) pv += __shfl_down(pv, off, 64);
        if (tid < nblk && (tid & 63) == 0) part[tid >> 6] = pv;
        __syncthreads();
        if (tid == 0) {
            float tot = 0.0f;
            for (int i = 0; i < (nblk + 63) / 64; ++i) tot += part[i];
            out[0] = tot * scale;
        }
    }
}

extern "C" void kernel_launch(void* const* d_in, const int* in_sizes, int n_in,
                              void* d_out, int out_size, void* d_ws, size_t ws_size,
                              hipStream_t stream) {
    const float* coord   = (const float*)d_in[0];
    const float* coord_t = (const float*)d_in[1];
    const float* Rm      = (const float*)d_in[2];
    const float* tv      = (const float*)d_in[3];

    const int B = in_sizes[2] / 9;            // R is [B,3,3]
    const int S = in_sizes[0] / (3 * B);      // coord is [B*S,3]
    const int NSC = S / SRC_BLK;              // 16
    const int nblk = B * NSC;                 // 256

    float* ws_part = (float*)d_ws;
    unsigned int* counter = (unsigned int*)((char*)d_ws + (size_t)nblk * 4);
    float* out = (float*)d_out;

    const size_t smem = (size_t)S * 16 + NW * 64 * P * 4 + 2 * 4 + 4;

    nn_fused_kernel<<<nblk, THREADS, smem, stream>>>(
        coord, coord_t, Rm, tv, ws_part, counter, out,
        S, NSC, nblk, 1.0f / ((float)B * (float)S));
}

// Round 5
// 16.394 us; speedup vs baseline: 1.1623x; 1.1623x over previous
//
#include <hip/hip_runtime.h>
#include <math.h>

// NN-MSE (one-directional Chamfer) loss, 2 dispatches, no cross-block atomics
// (R4 lesson: agent-scope release/acquire forces per-XCD L2 writebacks, +5us).
//
//  k1: 256 blocks (16 segs x 8 src-chunks x 2 target-halves), 512 thr = 8 waves.
//      Each block: 256 sources (P=4 per lane), min over its 1024-target half
//      staged in LDS as (-2x,-2y,-2z,|t|^2). Writes per-source half-min.
//      LDS law: reads/chip = evals/(64*P); P=4 halves R3's LDS time.
//  k2: ONE block, 1024 thr: min of the 2 halves per source, clamp, sum -> loss.

#define THREADS 512      // 8 waves
#define NW 8
#define P 4
#define SRC_BLK 256      // 64 lanes * P
#define TSPLIT 2

__global__ __launch_bounds__(THREADS)
void nn_half_kernel(const float* __restrict__ coord,
                    const float* __restrict__ coord_t,
                    const float* __restrict__ Rm,
                    const float* __restrict__ tv,
                    float* __restrict__ slice_min,   // [TSPLIT][B*S]
                    int S, int NSC, int BS) {
    __shared__ float4 tile[1024];                    // S/TSPLIT targets, 16KB
    __shared__ float  part[NW * SRC_BLK];            // 8KB

    const int tid  = threadIdx.x;
    const int bid  = blockIdx.x;
    const int b    = bid / (NSC * TSPLIT);
    const int rem  = bid - b * (NSC * TSPLIT);
    const int sc   = rem / TSPLIT;
    const int ts   = rem - sc * TSPLIT;
    const int w    = tid >> 6;
    const int lane = tid & 63;
    const int halfS = S / TSPLIT;                    // 1024

    // ---- stage this half's targets as (-2x,-2y,-2z,|t|^2); 4 pts/thread ----
    {
        const float* tb = coord_t + ((size_t)b * S + (size_t)ts * halfS) * 3;
        for (int base = tid * 4; base < halfS; base += THREADS * 4) {
            const float4* g4 = reinterpret_cast<const float4*>(tb + (size_t)base * 3);
            const float4 q0 = g4[0], q1 = g4[1], q2 = g4[2];
            const float px[4] = {q0.x, q0.w, q1.z, q2.y};
            const float py[4] = {q0.y, q1.x, q1.w, q2.z};
            const float pz[4] = {q0.z, q1.y, q2.x, q2.w};
            #pragma unroll
            for (int k = 0; k < 4; ++k) {
                const float x = px[k], y = py[k], z = pz[k];
                tile[base + k] = make_float4(-2.f*x, -2.f*y, -2.f*z,
                                             x*x + y*y + z*z);
            }
        }
    }

    // ---- rigid transform params (block-uniform) ----
    const float* Rb = Rm + (size_t)b * 9;
    const float r00=Rb[0], r01=Rb[1], r02=Rb[2];
    const float r10=Rb[3], r11=Rb[4], r12=Rb[5];
    const float r20=Rb[6], r21=Rb[7], r22=Rb[8];
    const float t0=tv[3*b], t1=tv[3*b+1], t2=tv[3*b+2];

    // ---- this lane's P=4 source points, transformed (3 float4 = 12 floats) ----
    float TX[P], TY[P], TZ[P], SN[P], best[P];
    {
        const float4* g4 = reinterpret_cast<const float4*>(
            coord + ((size_t)b * S + (size_t)sc * SRC_BLK + lane * P) * 3);
        const float4 q0 = g4[0], q1 = g4[1], q2 = g4[2];
        const float f[12] = {q0.x,q0.y,q0.z,q0.w, q1.x,q1.y,q1.z,q1.w,
                             q2.x,q2.y,q2.z,q2.w};
        #pragma unroll
        for (int j = 0; j < P; ++j) {
            const float x = f[3*j], y = f[3*j+1], z = f[3*j+2];
            const float sx = __builtin_fmaf(r00,x,__builtin_fmaf(r01,y,__builtin_fmaf(r02,z,t0)));
            const float sy = __builtin_fmaf(r10,x,__builtin_fmaf(r11,y,__builtin_fmaf(r12,z,t1)));
            const float sz = __builtin_fmaf(r20,x,__builtin_fmaf(r21,y,__builtin_fmaf(r22,z,t2)));
            TX[j]=sx; TY[j]=sy; TZ[j]=sz;
            SN[j]=sx*sx + sy*sy + sz*sz;
            best[j] = 3.0e38f;
        }
    }

    __syncthreads();

    // ---- main loop: wave w scans its 128 targets, 4 per iteration ----
    const int mbase = w * (halfS / NW);
    #pragma unroll 2
    for (int it = 0; it < (halfS / NW) / 4; ++it) {
        const float4 p0 = tile[mbase + 4*it + 0];
        const float4 p1 = tile[mbase + 4*it + 1];
        const float4 p2 = tile[mbase + 4*it + 2];
        const float4 p3 = tile[mbase + 4*it + 3];
        #pragma unroll
        for (int j = 0; j < P; ++j) {
            const float v0 = __builtin_fmaf(p0.x,TX[j],__builtin_fmaf(p0.y,TY[j],__builtin_fmaf(p0.z,TZ[j],p0.w)));
            const float v1 = __builtin_fmaf(p1.x,TX[j],__builtin_fmaf(p1.y,TY[j],__builtin_fmaf(p1.z,TZ[j],p1.w)));
            const float v2 = __builtin_fmaf(p2.x,TX[j],__builtin_fmaf(p2.y,TY[j],__builtin_fmaf(p2.z,TZ[j],p2.w)));
            const float v3 = __builtin_fmaf(p3.x,TX[j],__builtin_fmaf(p3.y,TY[j],__builtin_fmaf(p3.z,TZ[j],p3.w)));
            best[j] = fminf(fminf(best[j], v0), v1);   // v_min3
            best[j] = fminf(fminf(best[j], v2), v3);   // v_min3
        }
    }

    // ---- fold |s|^2; min across 8 waves; write per-source half-min ----
    #pragma unroll
    for (int j = 0; j < P; ++j)
        part[w * SRC_BLK + lane * P + j] = best[j] + SN[j];
    __syncthreads();

    if (tid < SRC_BLK) {
        float mn = part[tid];                          // stride-1, conflict-free
        #pragma unroll
        for (int ww = 1; ww < NW; ++ww)
            mn = fminf(mn, part[ww * SRC_BLK + tid]);
        slice_min[(size_t)ts * BS + (size_t)b * S + (size_t)sc * SRC_BLK + tid] = mn;
    }
}

__global__ __launch_bounds__(1024)
void combine_final_kernel(const float* __restrict__ slice_min,
                          float* __restrict__ out, int BS, float scale) {
    __shared__ float sm[16];
    const float4* s0 = reinterpret_cast<const float4*>(slice_min);
    const float4* s1 = reinterpret_cast<const float4*>(slice_min + BS);
    const int n4 = BS / 4;

    float acc = 0.0f;
    for (int i = threadIdx.x; i < n4; i += 1024) {
        const float4 a = s0[i];
        const float4 c = s1[i];
        const float m0 = fmaxf(fminf(a.x, c.x), 0.0f);
        const float m1 = fmaxf(fminf(a.y, c.y), 0.0f);
        const float m2 = fmaxf(fminf(a.z, c.z), 0.0f);
        const float m3 = fmaxf(fminf(a.w, c.w), 0.0f);
        acc += (m0 + m1) + (m2 + m3);
    }
    #pragma unroll
    for (int off = 32; off > 0; off >>= 1) acc += __shfl_down(acc, off, 64);
    if ((threadIdx.x & 63) == 0) sm[threadIdx.x >> 6] = acc;
    __syncthreads();
    if (threadIdx.x == 0) {
        float tot = 0.0f;
        #pragma unroll
        for (int i = 0; i < 16; ++i) tot += sm[i];
        out[0] = tot * scale;
    }
}

extern "C" void kernel_launch(void* const* d_in, const int* in_sizes, int n_in,
                              void* d_out, int out_size, void* d_ws, size_t ws_size,
                              hipStream_t stream) {
    const float* coord   = (const float*)d_in[0];
    const float* coord_t = (const float*)d_in[1];
    const float* Rm      = (const float*)d_in[2];
    const float* tv      = (const float*)d_in[3];

    const int B = in_sizes[2] / 9;            // R is [B,3,3]
    const int S = in_sizes[0] / (3 * B);      // coord is [B*S,3]
    const int BS = B * S;
    const int NSC = S / SRC_BLK;              // 8
    const int nblk = B * NSC * TSPLIT;        // 256

    float* slice_min = (float*)d_ws;          // TSPLIT * BS floats (256 KB)
    float* out = (float*)d_out;

    nn_half_kernel<<<nblk, THREADS, 0, stream>>>(
        coord, coord_t, Rm, tv, slice_min, S, NSC, BS);

    combine_final_kernel<<<1, 1024, 0, stream>>>(
        slice_min, out, BS, 1.0f / (float)BS);
}